// Round 7
// baseline (1400.746 us; speedup 1.0000x reference)
//
#include <hip/hip_runtime.h>
#include <hip/hip_cooperative_groups.h>

namespace cg = cooperative_groups;

#define HID 64
#define INDIM 128

typedef unsigned short ushort_t;
typedef unsigned int uint_t;

__device__ __forceinline__ float softplusf(float x) {
    return fmaxf(x, 0.f) + log1pf(expf(-fabsf(x)));
}
__device__ __forceinline__ ushort_t f2bf(float f) {
    union { float f; uint_t i; } c; c.f = f;
    uint_t u = c.i;
    u += 0x7FFFu + ((u >> 16) & 1u);   // round to nearest even
    return (ushort_t)(u >> 16);
}
__device__ __forceinline__ float bf2f(ushort_t u) {
    union { uint_t i; float f; } c; c.i = ((uint_t)u) << 16; return c.f;
}
__device__ __forceinline__ float lo_bf(uint_t u) {
    union { uint_t i; float f; } c; c.i = u << 16; return c.f;
}
__device__ __forceinline__ float hi_bf(uint_t u) {
    union { uint_t i; float f; } c; c.i = u & 0xFFFF0000u; return c.f;
}

// ---------------- H = x @ W, output bf16 (separate kernel: 66KB LDS) -------
__global__ __launch_bounds__(256) void k_gemm(const float* __restrict__ x,
                                              const float* __restrict__ W,
                                              ushort_t* __restrict__ Hb, int N) {
    __shared__ float Xs[64 * 132];
    __shared__ float Ws[128 * 64];
    int tid = threadIdx.x;
    int row0 = blockIdx.x * 64;

    const float4* W4 = (const float4*)W;
    float4* Ws4 = (float4*)Ws;
#pragma unroll
    for (int i = 0; i < 8; i++) Ws4[tid + 256 * i] = W4[tid + 256 * i];

#pragma unroll
    for (int i = 0; i < 8; i++) {
        int j = tid + 256 * i;
        int r = j >> 5, c4 = j & 31;
        int row = row0 + r;
        float4 v = make_float4(0.f, 0.f, 0.f, 0.f);
        if (row < N) v = *(const float4*)(x + row * INDIM + c4 * 4);
        *(float4*)(&Xs[r * 132 + c4 * 4]) = v;
    }
    __syncthreads();

    int tx = tid & 15;
    int ty = tid >> 4;
    float acc[4][4] = {};
    const float* xa = &Xs[(ty * 4) * 132];
#pragma unroll 4
    for (int k = 0; k < 128; k++) {
        float4 b = *(const float4*)(&Ws[k * 64 + tx * 4]);
#pragma unroll
        for (int i = 0; i < 4; i++) {
            float a = xa[i * 132 + k];
            acc[i][0] = fmaf(a, b.x, acc[i][0]);
            acc[i][1] = fmaf(a, b.y, acc[i][1]);
            acc[i][2] = fmaf(a, b.z, acc[i][2]);
            acc[i][3] = fmaf(a, b.w, acc[i][3]);
        }
    }
#pragma unroll
    for (int i = 0; i < 4; i++) {
        int row = row0 + ty * 4 + i;
        if (row < N) {
            ushort4 o;
            o.x = f2bf(acc[i][0]); o.y = f2bf(acc[i][1]);
            o.z = f2bf(acc[i][2]); o.w = f2bf(acc[i][3]);
            *(ushort4*)(&Hb[(size_t)row * HID + tx * 4]) = o;
        }
    }
}

// ---------------- one cooperative mega-kernel for everything else ----------
__global__ __launch_bounds__(256, 8) void k_mega(
    const int* __restrict__ src, const int* __restrict__ dst,
    const int* __restrict__ perm, const ushort_t* __restrict__ Hb,
    const float* __restrict__ bvec, const float* __restrict__ avec,
    const float* __restrict__ Wd,
    int* cnt, int* rowptr, int* cursor, float* dinv, int* partial,
    int2* csr, ushort_t* posb, ushort_t* negb, float* smallb,
    float* out, int N, int E)
{
    cg::grid_group grid = cg::this_grid();
    int tid = threadIdx.x;
    int bid = blockIdx.x;
    int gsize = gridDim.x * 256;
    int g = bid * 256 + tid;
    float* sumvec = smallb;
    float* lossAcc = smallb + 128;

    __shared__ int redC[256];
    __shared__ int sp[128];
    __shared__ int sc[256];
    __shared__ float redF[4][64];
    __shared__ float summ[64];
    __shared__ float svecS[64];
    __shared__ float redL[8];

    // ---- A: zero cnt + small accumulators ----
    for (int i = g; i < N; i += gsize) cnt[i] = 0;
    if (g < 130) smallb[g] = 0.f;
    grid.sync();

    // ---- B: degree histogram ----
    for (int e = g; e < E; e += gsize) atomicAdd(&cnt[dst[e]], 1);
    grid.sync();

    // ---- C: per-1024-chunk sums (blocks < B98) ----
    int B98 = (N + 1023) >> 10;
    if (bid < B98) {
        int base = bid << 10;
        int s = 0;
        for (int i = tid; i < 1024; i += 256) {
            int idx = base + i;
            if (idx < N) s += cnt[idx];
        }
        redC[tid] = s;
        __syncthreads();
        for (int off = 128; off; off >>= 1) {
            if (tid < off) redC[tid] += redC[tid + off];
            __syncthreads();
        }
        if (tid == 0) partial[bid] = redC[0];
    }
    grid.sync();

    // ---- D: redundant in-LDS scan of partials + per-chunk rowptr ----
    if (tid < 128) sp[tid] = (tid < B98) ? partial[tid] : 0;
    __syncthreads();
    for (int off = 1; off < 128; off <<= 1) {
        int v = (tid < 128 && tid >= off) ? sp[tid - off] : 0;
        __syncthreads();
        if (tid < 128) sp[tid] += v;
        __syncthreads();
    }
    if (bid < B98) {
        int chunkEx = sp[bid] - partial[bid];   // exclusive prefix of this chunk
        int base = bid << 10;
        int i0 = base + tid * 4;
        int v0 = 0, v1 = 0, v2 = 0, v3 = 0;
        if (i0 + 3 < N) {
            int4 c = *(const int4*)(cnt + i0);
            v0 = c.x; v1 = c.y; v2 = c.z; v3 = c.w;
        } else {
            if (i0 < N)     v0 = cnt[i0];
            if (i0 + 1 < N) v1 = cnt[i0 + 1];
            if (i0 + 2 < N) v2 = cnt[i0 + 2];
            if (i0 + 3 < N) v3 = cnt[i0 + 3];
        }
        int s = v0 + v1 + v2 + v3;
        sc[tid] = s;
        __syncthreads();
        for (int off = 1; off < 256; off <<= 1) {
            int t = (tid >= off) ? sc[tid - off] : 0;
            __syncthreads();
            sc[tid] += t;
            __syncthreads();
        }
        int ex = sc[tid] - s + chunkEx;
        int r0 = ex, r1 = ex + v0, r2 = ex + v0 + v1, r3 = ex + v0 + v1 + v2;
        if (i0 < N)     { rowptr[i0]   = r0; cursor[i0]   = r0; dinv[i0]   = rsqrtf((float)(v0 + 1)); }
        if (i0 + 1 < N) { rowptr[i0+1] = r1; cursor[i0+1] = r1; dinv[i0+1] = rsqrtf((float)(v1 + 1)); }
        if (i0 + 2 < N) { rowptr[i0+2] = r2; cursor[i0+2] = r2; dinv[i0+2] = rsqrtf((float)(v2 + 1)); }
        if (i0 + 3 < N) { rowptr[i0+3] = r3; cursor[i0+3] = r3; dinv[i0+3] = rsqrtf((float)(v3 + 1)); }
    }
    if (g == 0) rowptr[N] = E;
    grid.sync();

    // ---- E: bucket fill csr[j] = {src, perm[src]} ----
    for (int e = g; e < E; e += gsize) {
        int d = dst[e], s = src[e];
        int j = atomicAdd(&cursor[d], 1);
        csr[j] = make_int2(s, perm[s]);
    }
    grid.sync();

    // ---- F: fused pull-gather + self-loop + bias + PReLU + colsum ----
    {
        int lane = tid & 63;
        int half = lane >> 5;
        int sub = lane & 31;
        int wid = g >> 6;
        int nw = gsize >> 6;
        const uint_t* H32 = (const uint_t*)Hb;     // row stride = 32 u32
        float2 b2 = ((const float2*)bvec)[sub];
        float2 a2 = ((const float2*)avec)[sub];
        float sum0 = 0.f, sum1 = 0.f;

        for (int n = wid; n < N; n += nw) {
            float dv = dinv[n];
            float w2 = dv * dv;
            int beg = rowptr[n], end = rowptr[n + 1];
            float accP0 = 0.f, accP1 = 0.f, accN0 = 0.f, accN1 = 0.f;
            for (int j = beg; j < end; j += 4) {
                int eA = j + half;
                int eB = j + 2 + half;
                bool vA = eA < end, vB = eB < end;
                int2 spA = vA ? csr[eA] : make_int2(0, 0);
                int2 spB = vB ? csr[eB] : make_int2(0, 0);
                float ndA = vA ? dinv[spA.x] * dv : 0.f;
                float ndB = vB ? dinv[spB.x] * dv : 0.f;
                uint_t upA = H32[spA.x * 32 + sub];
                uint_t unA = H32[spA.y * 32 + sub];
                uint_t upB = H32[spB.x * 32 + sub];
                uint_t unB = H32[spB.y * 32 + sub];
                accP0 = fmaf(lo_bf(upA), ndA, accP0);
                accP1 = fmaf(hi_bf(upA), ndA, accP1);
                accN0 = fmaf(lo_bf(unA), ndA, accN0);
                accN1 = fmaf(hi_bf(unA), ndA, accN1);
                accP0 = fmaf(lo_bf(upB), ndB, accP0);
                accP1 = fmaf(hi_bf(upB), ndB, accP1);
                accN0 = fmaf(lo_bf(unB), ndB, accN0);
                accN1 = fmaf(hi_bf(unB), ndB, accN1);
            }
            accP0 += __shfl_xor(accP0, 32);
            accP1 += __shfl_xor(accP1, 32);
            accN0 += __shfl_xor(accN0, 32);
            accN1 += __shfl_xor(accN1, 32);
            int selfrow = half ? perm[n] : n;
            uint_t us = H32[selfrow * 32 + sub];
            float e0 = half ? accN0 : accP0;
            float e1 = half ? accN1 : accP1;
            float v0 = fmaf(lo_bf(us), w2, e0) + b2.x;
            float v1 = fmaf(hi_bf(us), w2, e1) + b2.y;
            v0 = v0 > 0.f ? v0 : v0 * a2.x;
            v1 = v1 > 0.f ? v1 : v1 * a2.y;
            uint_t packed = ((uint_t)f2bf(v1) << 16) | (uint_t)f2bf(v0);
            uint_t* outp = (uint_t*)(half ? negb : posb);
            outp[n * 32 + sub] = packed;
            if (!half) { sum0 += v0; sum1 += v1; }
        }

        int w = tid >> 6;
        if (!half) { redF[w][2 * sub] = sum0; redF[w][2 * sub + 1] = sum1; }
        __syncthreads();
        if (tid < 64) {
            float s = redF[0][tid] + redF[1][tid] + redF[2][tid] + redF[3][tid];
            atomicAdd(&sumvec[tid], s);
        }
    }
    grid.sync();

    // ---- G: per-block svec + loss ----
    {
        if (tid < 64) summ[tid] = 1.f / (1.f + expf(-sumvec[tid] / (float)N));
        __syncthreads();
        if (tid < 64) {
            float s = 0.f;
#pragma unroll
            for (int j = 0; j < 64; j++) s += Wd[tid * 64 + j] * summ[j];
            svecS[tid] = s;
        }
        __syncthreads();

        int lane = tid & 63;
        int half = lane >> 5;
        int sub = lane & 31;
        int w = tid >> 6;
        float s0 = svecS[2 * sub], s1 = svecS[2 * sub + 1];
        const uint_t* P32 = (const uint_t*)(half ? negb : posb);
        float l = 0.f;
        int wid = g >> 6, nw = gsize >> 6;
        for (int n = wid; n < N; n += nw) {
            uint_t u = P32[n * 32 + sub];
            float p = lo_bf(u) * s0 + hi_bf(u) * s1;
            p += __shfl_xor(p, 1);
            p += __shfl_xor(p, 2);
            p += __shfl_xor(p, 4);
            p += __shfl_xor(p, 8);
            p += __shfl_xor(p, 16);
            if (sub == 0) l += half ? softplusf(p) : softplusf(-p);
        }
        if (sub == 0) redL[w * 2 + half] = l;
        __syncthreads();
        if (tid == 0) {
            float t = 0.f;
#pragma unroll
            for (int i = 0; i < 8; i++) t += redL[i];
            atomicAdd(&lossAcc[0], t);
        }
    }
    grid.sync();

    // ---- H: final scalar ----
    if (g == 0) out[0] = lossAcc[0] / (float)N;
}

// ================= fallback path kernels (proven R5 sequence) ==============
__global__ __launch_bounds__(256) void k_count(const int* __restrict__ dst,
                                               int* __restrict__ cnt, int E) {
    int e = blockIdx.x * 256 + threadIdx.x;
    if (e < E) atomicAdd(&cnt[dst[e]], 1);
}

__global__ __launch_bounds__(256) void k_scan1(const int* __restrict__ cnt,
                                               int* __restrict__ partial, int N) {
    __shared__ int red[256];
    int base = blockIdx.x * 1024;
    int s = 0;
    for (int i = threadIdx.x; i < 1024; i += 256) {
        int idx = base + i;
        if (idx < N) s += cnt[idx];
    }
    red[threadIdx.x] = s;
    __syncthreads();
    for (int off = 128; off; off >>= 1) {
        if (threadIdx.x < off) red[threadIdx.x] += red[threadIdx.x + off];
        __syncthreads();
    }
    if (threadIdx.x == 0) partial[blockIdx.x] = red[0];
}

__global__ __launch_bounds__(128) void k_scan2(int* partial, int B) {
    __shared__ int s[128];
    int t = threadIdx.x;
    int v = (t < B) ? partial[t] : 0;
    s[t] = v;
    __syncthreads();
    for (int off = 1; off < 128; off <<= 1) {
        int tmp = (t >= off) ? s[t - off] : 0;
        __syncthreads();
        s[t] += tmp;
        __syncthreads();
    }
    if (t < B) partial[t] = s[t] - v;   // exclusive
}

__global__ __launch_bounds__(256) void k_scan3(const int* __restrict__ cnt,
                                               const int* __restrict__ partial,
                                               int* __restrict__ rowptr,
                                               int* __restrict__ cursor,
                                               float* __restrict__ dinv,
                                               int N, int E) {
    __shared__ int sc[256];
    int base = blockIdx.x * 1024;
    int i0 = base + threadIdx.x * 4;
    int v0 = 0, v1 = 0, v2 = 0, v3 = 0;
    if (i0 + 3 < N) {
        int4 c = *(const int4*)(cnt + i0);
        v0 = c.x; v1 = c.y; v2 = c.z; v3 = c.w;
    } else {
        if (i0 < N)     v0 = cnt[i0];
        if (i0 + 1 < N) v1 = cnt[i0 + 1];
        if (i0 + 2 < N) v2 = cnt[i0 + 2];
        if (i0 + 3 < N) v3 = cnt[i0 + 3];
    }
    int s = v0 + v1 + v2 + v3;
    sc[threadIdx.x] = s;
    __syncthreads();
    for (int off = 1; off < 256; off <<= 1) {
        int t = (threadIdx.x >= off) ? sc[threadIdx.x - off] : 0;
        __syncthreads();
        sc[threadIdx.x] += t;
        __syncthreads();
    }
    int ex = sc[threadIdx.x] - s + partial[blockIdx.x];
    int r0 = ex, r1 = ex + v0, r2 = ex + v0 + v1, r3 = ex + v0 + v1 + v2;
    if (i0 < N)     { rowptr[i0]   = r0; cursor[i0]   = r0; dinv[i0]   = rsqrtf((float)(v0 + 1)); }
    if (i0 + 1 < N) { rowptr[i0+1] = r1; cursor[i0+1] = r1; dinv[i0+1] = rsqrtf((float)(v1 + 1)); }
    if (i0 + 2 < N) { rowptr[i0+2] = r2; cursor[i0+2] = r2; dinv[i0+2] = rsqrtf((float)(v2 + 1)); }
    if (i0 + 3 < N) { rowptr[i0+3] = r3; cursor[i0+3] = r3; dinv[i0+3] = rsqrtf((float)(v3 + 1)); }
    if (blockIdx.x == 0 && threadIdx.x == 0) rowptr[N] = E;
}

__global__ __launch_bounds__(256) void k_fill(const int* __restrict__ src,
                                              const int* __restrict__ dst,
                                              const int* __restrict__ perm,
                                              int* __restrict__ cursor,
                                              int2* __restrict__ csr, int E) {
    int e = blockIdx.x * 256 + threadIdx.x;
    if (e >= E) return;
    int d = dst[e], s = src[e];
    int j = atomicAdd(&cursor[d], 1);
    csr[j] = make_int2(s, perm[s]);
}

__global__ __launch_bounds__(256) void k_gather(const ushort_t* __restrict__ Hb,
                                                const int* __restrict__ rowptr,
                                                const int2* __restrict__ csr,
                                                const int* __restrict__ perm,
                                                const float* __restrict__ dinv,
                                                const float* __restrict__ b,
                                                const float* __restrict__ a,
                                                ushort_t* __restrict__ posb,
                                                ushort_t* __restrict__ negb,
                                                float* __restrict__ sumvec, int N) {
    int tid = threadIdx.x;
    int lane = tid & 63;
    int half = lane >> 5;
    int sub = lane & 31;
    int wid = (blockIdx.x * 256 + tid) >> 6;
    int nw = gridDim.x * 4;
    const uint_t* H32 = (const uint_t*)Hb;
    float2 b2 = ((const float2*)b)[sub];
    float2 a2 = ((const float2*)a)[sub];
    float sum0 = 0.f, sum1 = 0.f;

    for (int n = wid; n < N; n += nw) {
        float dv = dinv[n];
        float w2 = dv * dv;
        int beg = rowptr[n], end = rowptr[n + 1];
        float accP0 = 0.f, accP1 = 0.f, accN0 = 0.f, accN1 = 0.f;
        for (int j = beg; j < end; j += 4) {
            int eA = j + half;
            int eB = j + 2 + half;
            bool vA = eA < end, vB = eB < end;
            int2 spA = vA ? csr[eA] : make_int2(0, 0);
            int2 spB = vB ? csr[eB] : make_int2(0, 0);
            float ndA = vA ? dinv[spA.x] * dv : 0.f;
            float ndB = vB ? dinv[spB.x] * dv : 0.f;
            uint_t upA = H32[spA.x * 32 + sub];
            uint_t unA = H32[spA.y * 32 + sub];
            uint_t upB = H32[spB.x * 32 + sub];
            uint_t unB = H32[spB.y * 32 + sub];
            accP0 = fmaf(lo_bf(upA), ndA, accP0);
            accP1 = fmaf(hi_bf(upA), ndA, accP1);
            accN0 = fmaf(lo_bf(unA), ndA, accN0);
            accN1 = fmaf(hi_bf(unA), ndA, accN1);
            accP0 = fmaf(lo_bf(upB), ndB, accP0);
            accP1 = fmaf(hi_bf(upB), ndB, accP1);
            accN0 = fmaf(lo_bf(unB), ndB, accN0);
            accN1 = fmaf(hi_bf(unB), ndB, accN1);
        }
        accP0 += __shfl_xor(accP0, 32);
        accP1 += __shfl_xor(accP1, 32);
        accN0 += __shfl_xor(accN0, 32);
        accN1 += __shfl_xor(accN1, 32);
        int selfrow = half ? perm[n] : n;
        uint_t us = H32[selfrow * 32 + sub];
        float e0 = half ? accN0 : accP0;
        float e1 = half ? accN1 : accP1;
        float v0 = fmaf(lo_bf(us), w2, e0) + b2.x;
        float v1 = fmaf(hi_bf(us), w2, e1) + b2.y;
        v0 = v0 > 0.f ? v0 : v0 * a2.x;
        v1 = v1 > 0.f ? v1 : v1 * a2.y;
        uint_t packed = ((uint_t)f2bf(v1) << 16) | (uint_t)f2bf(v0);
        uint_t* outp = (uint_t*)(half ? negb : posb);
        outp[n * 32 + sub] = packed;
        if (!half) { sum0 += v0; sum1 += v1; }
    }

    __shared__ float red[4][64];
    int w = tid >> 6;
    if (!half) { red[w][2 * sub] = sum0; red[w][2 * sub + 1] = sum1; }
    __syncthreads();
    if (tid < 64) {
        float s = red[0][tid] + red[1][tid] + red[2][tid] + red[3][tid];
        atomicAdd(&sumvec[tid], s);
    }
}

__global__ void k_disc(const float* __restrict__ sumvec, const float* __restrict__ Wd,
                       float* __restrict__ svec, int N) {
    __shared__ float summ[64];
    int t = threadIdx.x;
    summ[t] = 1.f / (1.f + expf(-sumvec[t] / (float)N));
    __syncthreads();
    float s = 0.f;
#pragma unroll
    for (int j = 0; j < 64; j++) s += Wd[t * 64 + j] * summ[j];
    svec[t] = s;
}

__global__ __launch_bounds__(256) void k_loss(const ushort_t* __restrict__ posb,
                                              const ushort_t* __restrict__ negb,
                                              const float* __restrict__ svec,
                                              float* __restrict__ lossAcc, int N) {
    int lane = threadIdx.x & 63;
    int wid = (blockIdx.x * 256 + threadIdx.x) >> 6;
    int nw = gridDim.x * 4;
    float sd = svec[lane];
    float l1 = 0.f, l2 = 0.f;
    for (int n = wid; n < N; n += nw) {
        float p = bf2f(posb[(size_t)n * HID + lane]) * sd;
        float q = bf2f(negb[(size_t)n * HID + lane]) * sd;
#pragma unroll
        for (int off = 32; off; off >>= 1) {
            p += __shfl_xor(p, off);
            q += __shfl_xor(q, off);
        }
        if (lane == 0) {
            l1 += softplusf(-p);
            l2 += softplusf(q);
        }
    }
    __shared__ float redA[4], redB[4];
    int w = threadIdx.x >> 6;
    if (lane == 0) { redA[w] = l1; redB[w] = l2; }
    __syncthreads();
    if (threadIdx.x == 0) {
        atomicAdd(&lossAcc[0], redA[0] + redA[1] + redA[2] + redA[3]);
        atomicAdd(&lossAcc[1], redB[0] + redB[1] + redB[2] + redB[3]);
    }
}

__global__ void k_final(const float* __restrict__ lossAcc, float* __restrict__ out, int N) {
    out[0] = (lossAcc[0] + lossAcc[1]) / (float)N;
}

extern "C" void kernel_launch(void* const* d_in, const int* in_sizes, int n_in,
                              void* d_out, int out_size, void* d_ws, size_t ws_size,
                              hipStream_t stream) {
    const float* x      = (const float*)d_in[0];
    const float* W_gcn  = (const float*)d_in[1];
    const float* b_gcn  = (const float*)d_in[2];
    const float* prelu_a= (const float*)d_in[3];
    const float* W_disc = (const float*)d_in[4];
    const int*   eidx   = (const int*)d_in[5];
    const int*   perm   = (const int*)d_in[6];

    int N = in_sizes[0] / INDIM;      // 100000
    int E = in_sizes[5] / 2;          // 1600000
    const int* src = eidx;
    const int* dst = eidx + E;

    // byte-offset workspace layout, 256B-aligned segments
    char* base = (char*)d_ws;
    size_t off = 0;
    auto alloc = [&](size_t bytes) { size_t o = off; off = (off + bytes + 255) & ~(size_t)255; return o; };
    ushort_t* Hb    = (ushort_t*)(base + alloc((size_t)N * HID * 2));
    ushort_t* posb  = (ushort_t*)(base + alloc((size_t)N * HID * 2));
    ushort_t* negb  = (ushort_t*)(base + alloc((size_t)N * HID * 2));
    int2*     csr   = (int2*)   (base + alloc((size_t)E * 8));
    int*      cnt   = (int*)    (base + alloc((size_t)N * 4));
    float*    smallb= (float*)  (base + alloc(130 * 4));
    int*      rowptr= (int*)    (base + alloc(((size_t)N + 1) * 4));
    int*      cursor= (int*)    (base + alloc((size_t)N * 4));
    float*    dinv  = (float*)  (base + alloc((size_t)N * 4));
    int*      partial=(int*)    (base + alloc(128 * 4));
    float*    outp  = (float*)d_out;
    float* sumvec = smallb;
    float* svec   = smallb + 64;
    float* lossAcc= smallb + 128;

    int nblk = (N + 63) / 64;
    k_gemm<<<nblk, 256, 0, stream>>>(x, W_gcn, Hb, N);

    // ---- size the cooperative launch from an occupancy query ----
    int numCU = 0, maxBpcu = 0;
    int dev = 0;
    hipGetDevice(&dev);
    hipDeviceGetAttribute(&numCU, hipDeviceAttributeMultiprocessorCount, dev);
    hipOccupancyMaxActiveBlocksPerMultiprocessor(&maxBpcu, k_mega, 256, 0);
    long long capBlocks = (long long)maxBpcu * (long long)numCU;
    int grid = (capBlocks > 2048) ? 2048 : (int)capBlocks;

    hipError_t cerr = hipErrorUnknown;
    if (grid >= 128) {
        void* args[] = {
            (void*)&src, (void*)&dst, (void*)&perm, (void*)&Hb,
            (void*)&b_gcn, (void*)&prelu_a, (void*)&W_disc,
            (void*)&cnt, (void*)&rowptr, (void*)&cursor, (void*)&dinv, (void*)&partial,
            (void*)&csr, (void*)&posb, (void*)&negb, (void*)&smallb,
            (void*)&outp, (void*)&N, (void*)&E
        };
        cerr = hipLaunchCooperativeKernel((void*)k_mega, dim3(grid), dim3(256),
                                          args, 0, stream);
    }

    if (cerr != hipSuccess) {
        // -------- fallback: proven multi-kernel sequence --------
        int B = (N + 1023) / 1024;
        hipMemsetAsync(cnt, 0, (size_t)N * 4, stream);
        hipMemsetAsync(smallb, 0, 130 * 4, stream);

        int nb = (E + 255) / 256;
        k_count<<<nb, 256, 0, stream>>>(dst, cnt, E);
        k_scan1<<<B, 256, 0, stream>>>(cnt, partial, N);
        k_scan2<<<1, 128, 0, stream>>>(partial, B);
        k_scan3<<<B, 256, 0, stream>>>(cnt, partial, rowptr, cursor, dinv, N, E);
        k_fill<<<nb, 256, 0, stream>>>(src, dst, perm, cursor, csr, E);
        k_gather<<<2048, 256, 0, stream>>>(Hb, rowptr, csr, perm, dinv, b_gcn, prelu_a,
                                           posb, negb, sumvec, N);
        k_disc<<<1, 64, 0, stream>>>(sumvec, W_disc, svec, N);
        k_loss<<<512, 256, 0, stream>>>(posb, negb, svec, lossAcc, N);
        k_final<<<1, 1, 0, stream>>>(lossAcc, outp, N);
    }
}

// Round 8
// 363.100 us; speedup vs baseline: 3.8577x; 3.8577x over previous
//
#include <hip/hip_runtime.h>

#define HID 64
#define INDIM 128

typedef unsigned short ushort_t;
typedef unsigned int uint_t;

__device__ __forceinline__ float softplusf(float x) {
    return fmaxf(x, 0.f) + log1pf(expf(-fabsf(x)));
}
__device__ __forceinline__ ushort_t f2bf(float f) {
    union { float f; uint_t i; } c; c.f = f;
    uint_t u = c.i;
    u += 0x7FFFu + ((u >> 16) & 1u);   // round to nearest even
    return (ushort_t)(u >> 16);
}
__device__ __forceinline__ float lo_bf(uint_t u) {
    union { uint_t i; float f; } c; c.i = u << 16; return c.f;
}
__device__ __forceinline__ float hi_bf(uint_t u) {
    union { uint_t i; float f; } c; c.i = u & 0xFFFF0000u; return c.f;
}

// ------ H = x @ W (bf16 out) + zero cnt/smallb (grid covers N exactly) -----
__global__ __launch_bounds__(256) void k_gemm(const float* __restrict__ x,
                                              const float* __restrict__ W,
                                              ushort_t* __restrict__ Hb,
                                              int* __restrict__ cnt,
                                              float* __restrict__ smallb, int N) {
    __shared__ float Xs[64 * 132];
    __shared__ float Ws[128 * 64];
    int tid = threadIdx.x;
    int row0 = blockIdx.x * 64;

    // fused zeroing: each block zeros its 64 cnt entries; block 0 zeros smallb
    if (tid < 64 && row0 + tid < N) cnt[row0 + tid] = 0;
    if (blockIdx.x == 0 && tid < 130) smallb[tid] = 0.f;

    const float4* W4 = (const float4*)W;
    float4* Ws4 = (float4*)Ws;
#pragma unroll
    for (int i = 0; i < 8; i++) Ws4[tid + 256 * i] = W4[tid + 256 * i];

#pragma unroll
    for (int i = 0; i < 8; i++) {
        int j = tid + 256 * i;
        int r = j >> 5, c4 = j & 31;
        int row = row0 + r;
        float4 v = make_float4(0.f, 0.f, 0.f, 0.f);
        if (row < N) v = *(const float4*)(x + row * INDIM + c4 * 4);
        *(float4*)(&Xs[r * 132 + c4 * 4]) = v;
    }
    __syncthreads();

    int tx = tid & 15;
    int ty = tid >> 4;
    float acc[4][4] = {};
    const float* xa = &Xs[(ty * 4) * 132];
#pragma unroll 4
    for (int k = 0; k < 128; k++) {
        float4 b = *(const float4*)(&Ws[k * 64 + tx * 4]);
#pragma unroll
        for (int i = 0; i < 4; i++) {
            float a = xa[i * 132 + k];
            acc[i][0] = fmaf(a, b.x, acc[i][0]);
            acc[i][1] = fmaf(a, b.y, acc[i][1]);
            acc[i][2] = fmaf(a, b.z, acc[i][2]);
            acc[i][3] = fmaf(a, b.w, acc[i][3]);
        }
    }
#pragma unroll
    for (int i = 0; i < 4; i++) {
        int row = row0 + ty * 4 + i;
        if (row < N) {
            ushort4 o;
            o.x = f2bf(acc[i][0]); o.y = f2bf(acc[i][1]);
            o.z = f2bf(acc[i][2]); o.w = f2bf(acc[i][3]);
            *(ushort4*)(&Hb[(size_t)row * HID + tx * 4]) = o;
        }
    }
}

// ---------------- degree histogram over dst --------------------------------
__global__ __launch_bounds__(256) void k_count(const int* __restrict__ dst,
                                               int* __restrict__ cnt, int E) {
    int e = blockIdx.x * 256 + threadIdx.x;
    if (e < E) atomicAdd(&cnt[dst[e]], 1);
}

// ---------------- scan stage 1: per-1024-chunk sums ------------------------
__global__ __launch_bounds__(256) void k_scan1(const int* __restrict__ cnt,
                                               int* __restrict__ partial, int N) {
    __shared__ int red[256];
    int base = blockIdx.x * 1024;
    int s = 0;
    for (int i = threadIdx.x; i < 1024; i += 256) {
        int idx = base + i;
        if (idx < N) s += cnt[idx];
    }
    red[threadIdx.x] = s;
    __syncthreads();
    for (int off = 128; off; off >>= 1) {
        if (threadIdx.x < off) red[threadIdx.x] += red[threadIdx.x + off];
        __syncthreads();
    }
    if (threadIdx.x == 0) partial[blockIdx.x] = red[0];
}

// ------ scan stage 2: redundant in-LDS scan of partials + per-chunk rowptr -
__global__ __launch_bounds__(256) void k_scan3(const int* __restrict__ cnt,
                                               const int* __restrict__ partial,
                                               int* __restrict__ rowptr,
                                               int* __restrict__ cursor,
                                               float* __restrict__ dinv,
                                               int N, int E) {
    __shared__ int sp[128];
    __shared__ int sc[256];
    int tid = threadIdx.x;
    int B98 = (N + 1023) >> 10;
    if (tid < 128) sp[tid] = (tid < B98) ? partial[tid] : 0;
    __syncthreads();
    for (int off = 1; off < 128; off <<= 1) {
        int v = (tid < 128 && tid >= off) ? sp[tid - off] : 0;
        __syncthreads();
        if (tid < 128) sp[tid] += v;
        __syncthreads();
    }
    int chunkEx = sp[blockIdx.x] - partial[blockIdx.x];   // exclusive chunk prefix
    __syncthreads();

    int base = blockIdx.x << 10;
    int i0 = base + tid * 4;
    int v0 = 0, v1 = 0, v2 = 0, v3 = 0;
    if (i0 + 3 < N) {
        int4 c = *(const int4*)(cnt + i0);
        v0 = c.x; v1 = c.y; v2 = c.z; v3 = c.w;
    } else {
        if (i0 < N)     v0 = cnt[i0];
        if (i0 + 1 < N) v1 = cnt[i0 + 1];
        if (i0 + 2 < N) v2 = cnt[i0 + 2];
        if (i0 + 3 < N) v3 = cnt[i0 + 3];
    }
    int s = v0 + v1 + v2 + v3;
    sc[tid] = s;
    __syncthreads();
    for (int off = 1; off < 256; off <<= 1) {
        int t = (tid >= off) ? sc[tid - off] : 0;
        __syncthreads();
        sc[tid] += t;
        __syncthreads();
    }
    int ex = sc[tid] - s + chunkEx;
    int r0 = ex, r1 = ex + v0, r2 = ex + v0 + v1, r3 = ex + v0 + v1 + v2;
    if (i0 < N)     { rowptr[i0]   = r0; cursor[i0]   = r0; dinv[i0]   = rsqrtf((float)(v0 + 1)); }
    if (i0 + 1 < N) { rowptr[i0+1] = r1; cursor[i0+1] = r1; dinv[i0+1] = rsqrtf((float)(v1 + 1)); }
    if (i0 + 2 < N) { rowptr[i0+2] = r2; cursor[i0+2] = r2; dinv[i0+2] = rsqrtf((float)(v2 + 1)); }
    if (i0 + 3 < N) { rowptr[i0+3] = r3; cursor[i0+3] = r3; dinv[i0+3] = rsqrtf((float)(v3 + 1)); }
    if (blockIdx.x == 0 && tid == 0) rowptr[N] = E;
}

// ------ bucket fill: csrS[j]={src,perm[src]}, csrN[j]=dinv[s]*dinv[d] ------
__global__ __launch_bounds__(256) void k_fill(const int* __restrict__ src,
                                              const int* __restrict__ dst,
                                              const int* __restrict__ perm,
                                              const float* __restrict__ dinv,
                                              int* __restrict__ cursor,
                                              int2* __restrict__ csrS,
                                              float* __restrict__ csrN, int E) {
    int e = blockIdx.x * 256 + threadIdx.x;
    if (e >= E) return;
    int d = dst[e], s = src[e];
    int j = atomicAdd(&cursor[d], 1);
    csrS[j] = make_int2(s, perm[s]);
    csrN[j] = dinv[s] * dinv[d];
}

// ------ fused pull-gather, prefetched csr, precomputed norms ---------------
__global__ __launch_bounds__(256) void k_gather(const ushort_t* __restrict__ Hb,
                                                const int* __restrict__ rowptr,
                                                const int2* __restrict__ csrS,
                                                const float* __restrict__ csrN,
                                                const int* __restrict__ perm,
                                                const float* __restrict__ dinv,
                                                const float* __restrict__ b,
                                                const float* __restrict__ a,
                                                ushort_t* __restrict__ posb,
                                                ushort_t* __restrict__ negb,
                                                float* __restrict__ sumvec, int N) {
    int tid = threadIdx.x;
    int lane = tid & 63;
    int half = lane >> 5;
    int sub = lane & 31;
    int wid = (blockIdx.x * 256 + tid) >> 6;
    int nw = gridDim.x * 4;
    const uint_t* H32 = (const uint_t*)Hb;     // row stride = 32 u32
    float2 b2 = ((const float2*)b)[sub];
    float2 a2 = ((const float2*)a)[sub];
    float sum0 = 0.f, sum1 = 0.f;

    for (int n = wid; n < N; n += nw) {
        float dv = dinv[n];
        float w2 = dv * dv;
        int beg = rowptr[n], end = rowptr[n + 1];
        float accP0 = 0.f, accP1 = 0.f, accN0 = 0.f, accN1 = 0.f;
        // prologue prefetch
        int eA = beg + half, eB = beg + 2 + half;
        bool vA = eA < end, vB = eB < end;
        int2 spA = vA ? csrS[eA] : make_int2(0, 0);
        int2 spB = vB ? csrS[eB] : make_int2(0, 0);
        float nmA = vA ? csrN[eA] : 0.f;
        float nmB = vB ? csrN[eB] : 0.f;
        for (int j = beg; j < end; j += 4) {
            // prefetch next quad's entries (independent of current H loads)
            int fA = j + 4 + half, fB = j + 6 + half;
            bool wA = fA < end, wB = fB < end;
            int2 npA = wA ? csrS[fA] : make_int2(0, 0);
            int2 npB = wB ? csrS[fB] : make_int2(0, 0);
            float nnA = wA ? csrN[fA] : 0.f;
            float nnB = wB ? csrN[fB] : 0.f;
            // current H gathers (one indirection only)
            uint_t upA = H32[spA.x * 32 + sub];
            uint_t unA = H32[spA.y * 32 + sub];
            uint_t upB = H32[spB.x * 32 + sub];
            uint_t unB = H32[spB.y * 32 + sub];
            accP0 = fmaf(lo_bf(upA), nmA, accP0);
            accP1 = fmaf(hi_bf(upA), nmA, accP1);
            accN0 = fmaf(lo_bf(unA), nmA, accN0);
            accN1 = fmaf(hi_bf(unA), nmA, accN1);
            accP0 = fmaf(lo_bf(upB), nmB, accP0);
            accP1 = fmaf(hi_bf(upB), nmB, accP1);
            accN0 = fmaf(lo_bf(unB), nmB, accN0);
            accN1 = fmaf(hi_bf(unB), nmB, accN1);
            spA = npA; spB = npB; nmA = nnA; nmB = nnB;
        }
        accP0 += __shfl_xor(accP0, 32);
        accP1 += __shfl_xor(accP1, 32);
        accN0 += __shfl_xor(accN0, 32);
        accN1 += __shfl_xor(accN1, 32);
        int selfrow = half ? perm[n] : n;
        uint_t us = H32[selfrow * 32 + sub];
        float e0 = half ? accN0 : accP0;
        float e1 = half ? accN1 : accP1;
        float v0 = fmaf(lo_bf(us), w2, e0) + b2.x;
        float v1 = fmaf(hi_bf(us), w2, e1) + b2.y;
        v0 = v0 > 0.f ? v0 : v0 * a2.x;
        v1 = v1 > 0.f ? v1 : v1 * a2.y;
        uint_t packed = ((uint_t)f2bf(v1) << 16) | (uint_t)f2bf(v0);
        uint_t* outp = (uint_t*)(half ? negb : posb);
        outp[n * 32 + sub] = packed;
        if (!half) { sum0 += v0; sum1 += v1; }
    }

    __shared__ float red[4][64];
    int w = tid >> 6;
    if (!half) { red[w][2 * sub] = sum0; red[w][2 * sub + 1] = sum1; }
    __syncthreads();
    if (tid < 64) {
        float s = red[0][tid] + red[1][tid] + red[2][tid] + red[3][tid];
        atomicAdd(&sumvec[tid], s);
    }
}

// ------ loss with fused discriminator (svec computed per-block) ------------
__global__ __launch_bounds__(256) void k_loss(const ushort_t* __restrict__ posb,
                                              const ushort_t* __restrict__ negb,
                                              const float* __restrict__ sumvec,
                                              const float* __restrict__ Wd,
                                              float* __restrict__ lossAcc, int N) {
    __shared__ float summ[64];
    __shared__ float svecS[64];
    __shared__ float redL[8];
    int tid = threadIdx.x;
    if (tid < 64) summ[tid] = 1.f / (1.f + expf(-sumvec[tid] / (float)N));
    __syncthreads();
    if (tid < 64) {
        float s = 0.f;
#pragma unroll
        for (int j = 0; j < 64; j++) s += Wd[tid * 64 + j] * summ[j];
        svecS[tid] = s;
    }
    __syncthreads();

    int lane = tid & 63;
    int half = lane >> 5;
    int sub = lane & 31;
    int w = tid >> 6;
    float s0 = svecS[2 * sub], s1 = svecS[2 * sub + 1];
    const uint_t* P32 = (const uint_t*)(half ? negb : posb);
    float l = 0.f;
    int wid = (blockIdx.x * 256 + tid) >> 6;
    int nw = gridDim.x * 4;
    for (int n = wid; n < N; n += nw) {
        uint_t u = P32[n * 32 + sub];
        float p = lo_bf(u) * s0 + hi_bf(u) * s1;
        p += __shfl_xor(p, 1);
        p += __shfl_xor(p, 2);
        p += __shfl_xor(p, 4);
        p += __shfl_xor(p, 8);
        p += __shfl_xor(p, 16);
        if (sub == 0) l += half ? softplusf(p) : softplusf(-p);
    }
    if (sub == 0) redL[w * 2 + half] = l;
    __syncthreads();
    if (tid == 0) {
        float t = 0.f;
#pragma unroll
        for (int i = 0; i < 8; i++) t += redL[i];
        atomicAdd(&lossAcc[0], t);
    }
}

// ---------------- final scalar ---------------------------------------------
__global__ void k_final(const float* __restrict__ lossAcc, float* __restrict__ out, int N) {
    out[0] = lossAcc[0] / (float)N;
}

extern "C" void kernel_launch(void* const* d_in, const int* in_sizes, int n_in,
                              void* d_out, int out_size, void* d_ws, size_t ws_size,
                              hipStream_t stream) {
    const float* x      = (const float*)d_in[0];
    const float* W_gcn  = (const float*)d_in[1];
    const float* b_gcn  = (const float*)d_in[2];
    const float* prelu_a= (const float*)d_in[3];
    const float* W_disc = (const float*)d_in[4];
    const int*   eidx   = (const int*)d_in[5];
    const int*   perm   = (const int*)d_in[6];

    int N = in_sizes[0] / INDIM;      // 100000
    int E = in_sizes[5] / 2;          // 1600000
    const int* src = eidx;
    const int* dst = eidx + E;

    // byte-offset workspace layout, 256B-aligned segments
    char* base = (char*)d_ws;
    size_t off = 0;
    auto alloc = [&](size_t bytes) { size_t o = off; off = (off + bytes + 255) & ~(size_t)255; return o; };
    ushort_t* Hb    = (ushort_t*)(base + alloc((size_t)N * HID * 2));
    ushort_t* posb  = (ushort_t*)(base + alloc((size_t)N * HID * 2));
    ushort_t* negb  = (ushort_t*)(base + alloc((size_t)N * HID * 2));
    int2*     csrS  = (int2*)   (base + alloc((size_t)E * 8));
    float*    csrN  = (float*)  (base + alloc((size_t)E * 4));
    int*      cnt   = (int*)    (base + alloc((size_t)N * 4));
    float*    smallb= (float*)  (base + alloc(130 * 4));
    int*      rowptr= (int*)    (base + alloc(((size_t)N + 1) * 4));
    int*      cursor= (int*)    (base + alloc((size_t)N * 4));
    float*    dinv  = (float*)  (base + alloc((size_t)N * 4));
    int*      partial=(int*)    (base + alloc(128 * 4));
    float* sumvec = smallb;
    float* lossAcc= smallb + 128;

    int B = (N + 1023) / 1024;            // 98
    int nbE = (E + 255) / 256;
    int nbG = (N + 63) / 64;              // 1563 == covers N for cnt zeroing

    k_gemm<<<nbG, 256, 0, stream>>>(x, W_gcn, Hb, cnt, smallb, N);
    k_count<<<nbE, 256, 0, stream>>>(dst, cnt, E);
    k_scan1<<<B, 256, 0, stream>>>(cnt, partial, N);
    k_scan3<<<B, 256, 0, stream>>>(cnt, partial, rowptr, cursor, dinv, N, E);
    k_fill<<<nbE, 256, 0, stream>>>(src, dst, perm, dinv, cursor, csrS, csrN, E);
    k_gather<<<2048, 256, 0, stream>>>(Hb, rowptr, csrS, csrN, perm, dinv,
                                       b_gcn, prelu_a, posb, negb, sumvec, N);
    k_loss<<<512, 256, 0, stream>>>(posb, negb, sumvec, W_disc, lossAcc, N);
    k_final<<<1, 1, 0, stream>>>(lossAcc, (float*)d_out, N);
}